// Round 5
// baseline (346.491 us; speedup 1.0000x reference)
//
#include <hip/hip_runtime.h>
#include <hip/hip_bf16.h>
#include <stdint.h>

// Problem constants: NA=NT=1024, A_DIM=E_DIM=128, L=128, K = L*128 = 16384

typedef short bf16x8 __attribute__((ext_vector_type(8)));
typedef float f32x4  __attribute__((ext_vector_type(4)));

#define GLD16(g, l) __builtin_amdgcn_global_load_lds( \
    (const __attribute__((address_space(1))) void*)(uintptr_t)(g), \
    (__attribute__((address_space(3))) void*)(uintptr_t)(l), 16, 0, 0)

// ---------------- prep: transpose inputs [1024][1024] -> inputsT ----------------
__global__ __launch_bounds__(256) void transpose_int_kernel(const int* __restrict__ in,
                                                            int* __restrict__ out) {
    __shared__ int tile[32][33];
    int b = blockIdx.x;              // 1024 tiles
    int tr = b >> 5, tc = b & 31;
    int r0 = tr * 32, c0 = tc * 32;
    int tx = threadIdx.x & 31, ty = threadIdx.x >> 5;
#pragma unroll
    for (int p = 0; p < 4; ++p)
        tile[ty + p * 8][tx] = in[(size_t)(r0 + ty + p * 8) * 1024 + c0 + tx];
    __syncthreads();
#pragma unroll
    for (int p = 0; p < 4; ++p) {
        int cc = ty + p * 8;
        out[(size_t)(c0 + cc) * 1024 + r0 + tx] = tile[tx][cc];
    }
}

// ------------- prep: transpose+cast weights f32 [16384][128] -> bf16 [128][16384] -------------
__global__ __launch_bounds__(256) void transpose_w_kernel(const float* __restrict__ W0,
                                                          const float* __restrict__ W1,
                                                          uint16_t* __restrict__ O0,
                                                          uint16_t* __restrict__ O1) {
    __shared__ float tile[32][33];
    int b = blockIdx.x;              // 4096 tiles (2048 per weight)
    const float* W = W0;
    uint16_t* O = O0;
    if (b >= 2048) { b -= 2048; W = W1; O = O1; }
    int tr = b >> 2, tc = b & 3;
    int r0 = tr * 32, c0 = tc * 32;
    int tx = threadIdx.x & 31, ty = threadIdx.x >> 5;
#pragma unroll
    for (int p = 0; p < 4; ++p)
        tile[ty + p * 8][tx] = W[(size_t)(r0 + ty + p * 8) * 128 + c0 + tx];
    __syncthreads();
#pragma unroll
    for (int p = 0; p < 4; ++p) {
        int cc = ty + p * 8;
        __hip_bfloat16 h = __float2bfloat16(tile[tx][cc]);
        O[(size_t)(c0 + cc) * 16384 + r0 + tx] = *(uint16_t*)&h;
    }
}

// ---------------- prep: CSR build — parallel deterministic counting sort ----------------
__global__ __launch_bounds__(128) void csr_build_kernel(const int* __restrict__ inA,
                                                        const int* __restrict__ inT,
                                                        uint16_t* __restrict__ idxA,
                                                        uint16_t* __restrict__ idxT,
                                                        int* __restrict__ offA,
                                                        int* __restrict__ offT) {
    __shared__ uint16_t chist[128][128];  // 32 KiB [chunk][label]
    __shared__ int lab[1024];
    __shared__ int tot[128];
    __shared__ int off[128];
    int b = blockIdx.x;
    const int* in = inA; uint16_t* idx = idxA; int* offo = offA; int row = b;
    if (b >= 1024) { in = inT; idx = idxT; offo = offT; row = b - 1024; }
    const int c = threadIdx.x;            // 0..127

    for (int i = c; i < 8192; i += 128) ((uint32_t*)chist)[i] = 0;
    for (int i = c; i < 1024; i += 128) lab[i] = in[(size_t)row * 1024 + i];
    __syncthreads();

    int mylab[8], rloc[8];
#pragma unroll
    for (int k = 0; k < 8; ++k) {
        int l = lab[c * 8 + k];
        mylab[k] = l;
        rloc[k] = chist[c][l];
        chist[c][l] = (uint16_t)(rloc[k] + 1);
    }
    __syncthreads();

    {   // column prefix over chunks: thread c owns label l=c
        int run = 0;
#pragma unroll 4
        for (int ch = 0; ch < 128; ++ch) {
            int v = chist[ch][c];
            chist[ch][c] = (uint16_t)run;
            run += v;
        }
        tot[c] = run;
    }
    __syncthreads();
    if (c == 0) {
        int s = 0;
#pragma unroll 4
        for (int l = 0; l < 128; ++l) { off[l] = s; s += tot[l]; }
    }
    __syncthreads();
    offo[(size_t)row * 128 + c] = off[c];
#pragma unroll
    for (int k = 0; k < 8; ++k) {
        int l = mylab[k];
        int pos = off[l] + (int)chist[c][l] + rloc[k];
        idx[(size_t)row * 1024 + pos] = (uint16_t)(c * 8 + k);
    }
}

// ---------------- prep: init output + bf16 mirrors ----------------
__global__ __launch_bounds__(256) void init_out_kernel(const float* __restrict__ fa,
                                                       const float* __restrict__ ft,
                                                       float* __restrict__ out,
                                                       uint16_t* __restrict__ srcAb,
                                                       uint16_t* __restrict__ srcTb) {
    int i = blockIdx.x * 256 + threadIdx.x;   // grid 2048 -> 524288
    int r = i >> 8, c = i & 255;
    float v = 0.f;
    if (c < 128) {
        v = (r < 1024) ? fa[(size_t)r * 128 + c] : ft[(size_t)(r - 1024) * 128 + c];
        __hip_bfloat16 h = __float2bfloat16(v);
        if (r < 1024) srcAb[(size_t)r * 128 + c] = *(uint16_t*)&h;
        else          srcTb[(size_t)(r - 1024) * 128 + c] = *(uint16_t*)&h;
    }
    out[i] = v;
}

// ---------------- mirror: state f32 (stride 256) -> bf16 (stride 128) ----------------
__global__ __launch_bounds__(256) void mirror_kernel(const float* __restrict__ state,
                                                     uint32_t* __restrict__ dst32) {
    int i = blockIdx.x * 256 + threadIdx.x;   // grid 256 -> 65536 threads, 2 floats each
    int idx2 = i * 2;
    int r = idx2 >> 7, c = idx2 & 127;
    float2 v = *(const float2*)(state + (size_t)r * 256 + c);
    __hip_bfloat16 h0 = __float2bfloat16(v.x), h1 = __float2bfloat16(v.y);
    dst32[i] = ((uint32_t)(*(uint16_t*)&h1) << 16) | (uint32_t)(*(uint16_t*)&h0);
}

// ---------------- fused bucket+GEMM phase ----------------
// Block (mt, lc): rows [mt*128, mt*128+128), labels {2lc, 2lc+1}. 8 waves.
// Per label: async-stage B slice (GLD16, inverse-swizzled source) while gathering
// bucket sums straight into the swizzled LDS A-tile; barrier; K=128 of MFMA.
// After both labels: atomic-add 128x128 partial into state (stride 256).
__global__ __launch_bounds__(512) void fused_phase_kernel(
    const uint16_t* __restrict__ idx,   // [1024][1024] CSR indices (sorted by label)
    const int* __restrict__ off,        // [1024][128] label offsets
    const uint32_t* __restrict__ srcb,  // [1024][64] packed bf16x2 source state
    const uint16_t* __restrict__ Bt,    // [128][16384] bf16 weights (n-major)
    float* __restrict__ state)          // [1024][256] f32 accumulator (d_out)
{
    __shared__ uint16_t Atile[128 * 128];   // 32 KiB  A[j][e], 16B-slot XOR-swizzled by row&15
    __shared__ uint16_t Btile[128 * 128];   // 32 KiB  B[n][k], same swizzle

    const int tid = threadIdx.x;
    const int lane = tid & 63, wv = tid >> 6;
    const int mt = blockIdx.x;          // 0..7
    const int lc = blockIdx.y;          // 0..63
    const int wr = wv >> 2, wc = wv & 3;

    f32x4 acc[4][2] = {};

    const int brr = lane >> 4;          // 0..3 (row within 4-row group)
    const int bx  = lane & 15;          // 16B slot

    for (int ls = 0; ls < 2; ++ls) {
        const int l = lc * 2 + ls;

        // ---- B stage: rows wv*16..wv*16+15, linear LDS dest + inverse-swizzled source ----
#pragma unroll
        for (int g = 0; g < 4; ++g) {
            int row = wv * 16 + g * 4 + brr;
            int sx = bx ^ (row & 15);
            const char* gB = (const char*)Bt + ((size_t)row * 16384 + l * 128 + sx * 8) * 2;
            char* lB = (char*)Btile + (wv * 16 + g * 4) * 256;   // +lane*16 by hardware
            GLD16(gB, lB);
        }

        // ---- gather A: wave handles 16 j-rows; lane covers channels 2lane,2lane+1 ----
#pragma unroll 1
        for (int jj = 0; jj < 16; ++jj) {
            int jl = wv * 16 + jj;
            int jg = mt * 128 + jl;
            const int* roff = off + (size_t)jg * 128;
            int s = roff[l];
            int e = (l < 127) ? roff[l + 1] : 1024;
            const uint16_t* ridx = idx + (size_t)jg * 1024;
            float a0 = 0.f, a1 = 0.f, b0 = 0.f, b1 = 0.f;
            int p = s;
            for (; p + 3 < e; p += 4) {
                uint32_t v0 = srcb[(size_t)ridx[p]     * 64 + lane];
                uint32_t v1 = srcb[(size_t)ridx[p + 1] * 64 + lane];
                uint32_t v2 = srcb[(size_t)ridx[p + 2] * 64 + lane];
                uint32_t v3 = srcb[(size_t)ridx[p + 3] * 64 + lane];
                a0 += __uint_as_float(v0 << 16) + __uint_as_float(v1 << 16);
                a1 += __uint_as_float(v0 & 0xffff0000u) + __uint_as_float(v1 & 0xffff0000u);
                b0 += __uint_as_float(v2 << 16) + __uint_as_float(v3 << 16);
                b1 += __uint_as_float(v2 & 0xffff0000u) + __uint_as_float(v3 & 0xffff0000u);
            }
            for (; p < e; ++p) {
                uint32_t v0 = srcb[(size_t)ridx[p] * 64 + lane];
                a0 += __uint_as_float(v0 << 16);
                a1 += __uint_as_float(v0 & 0xffff0000u);
            }
            float r0 = a0 + b0, r1 = a1 + b1;
            __hip_bfloat16 h0 = __float2bfloat16(r0), h1 = __float2bfloat16(r1);
            uint32_t pk = ((uint32_t)(*(uint16_t*)&h1) << 16) | (uint32_t)(*(uint16_t*)&h0);
            int phys = (lane >> 2) ^ (jl & 15);
            *(uint32_t*)((char*)Atile + jl * 256 + phys * 16 + (lane & 3) * 4) = pk;
        }
        __syncthreads();   // drains GLD16 vmcnt + orders LDS writes

        // ---- MFMA: wave tile 64x32, K=128 ----
        {
            const int q = lane >> 4, rl = lane & 15;
#pragma unroll
            for (int kk = 0; kk < 4; ++kk) {
                bf16x8 af[4], bfr[2];
#pragma unroll
                for (int m = 0; m < 4; ++m) {
                    int row = wr * 64 + m * 16 + rl;
                    int sw = (kk * 4 + q) ^ (row & 15);
                    af[m] = *(const bf16x8*)((const char*)Atile + row * 256 + sw * 16);
                }
#pragma unroll
                for (int n = 0; n < 2; ++n) {
                    int row = wc * 32 + n * 16 + rl;
                    int sw = (kk * 4 + q) ^ (row & 15);
                    bfr[n] = *(const bf16x8*)((const char*)Btile + row * 256 + sw * 16);
                }
#pragma unroll
                for (int m = 0; m < 4; ++m)
#pragma unroll
                    for (int n = 0; n < 2; ++n)
                        acc[m][n] = __builtin_amdgcn_mfma_f32_16x16x32_bf16(af[m], bfr[n], acc[m][n], 0, 0, 0);
            }
        }
        __syncthreads();   // before next label overwrites A/B tiles
    }

    // ---- epilogue: C/D layout col=lane&15, row=(lane>>4)*4+reg ----
    const int rq = lane >> 4, cn = lane & 15;
#pragma unroll
    for (int m = 0; m < 4; ++m)
#pragma unroll
        for (int n = 0; n < 2; ++n)
#pragma unroll
            for (int r = 0; r < 4; ++r) {
                int row = mt * 128 + wr * 64 + m * 16 + rq * 4 + r;
                int col = wc * 32 + n * 16 + cn;
                unsafeAtomicAdd(&state[(size_t)row * 256 + col], acc[m][n][r]);
            }
}

extern "C" void kernel_launch(void* const* d_in, const int* in_sizes, int n_in,
                              void* d_out, int out_size, void* d_ws, size_t ws_size,
                              hipStream_t stream) {
    const int*   inputs  = (const int*)d_in[0];
    const float* first_a = (const float*)d_in[1];
    const float* first_t = (const float*)d_in[2];
    const float* Awij    = (const float*)d_in[3];
    const float* Awij2   = (const float*)d_in[4];
    float* out = (float*)d_out;

    // workspace layout (18 MiB total)
    char* w = (char*)d_ws;
    int*      inputsT = (int*)(w);                      // 4 MiB (prep-only)
    uint16_t* BtA     = (uint16_t*)(w + (4u << 20));    // 4 MiB  [a][l*128+e] = Awij2[l][e][a]
    uint16_t* BtT     = (uint16_t*)(w + (8u << 20));    // 4 MiB  [e][l*128+a] = Awij[l][a][e]
    uint16_t* idxA    = (uint16_t*)(w + (12u << 20));   // 2 MiB
    uint16_t* idxT    = (uint16_t*)(w + (14u << 20));   // 2 MiB
    int*      offA    = (int*)(w + (16u << 20));        // 512 KiB
    int*      offT    = (int*)(w + (16u << 20) + (1u << 19)); // 512 KiB
    uint16_t* srcAb   = (uint16_t*)(w + (17u << 20));   // 256 KiB bf16 mirror of stateA
    uint16_t* srcTb   = (uint16_t*)(w + (17u << 20) + (1u << 18)); // 256 KiB mirror of stateT
    if (ws_size < (18u << 20)) return;

    float* stateA = out;                 // [1024][256], cols 0..127 live
    float* stateT = out + 1024 * 256;    // [1024][256], cols 0..127 live

    transpose_int_kernel<<<1024, 256, 0, stream>>>(inputs, inputsT);
    transpose_w_kernel<<<4096, 256, 0, stream>>>(Awij2, Awij, BtA, BtT);
    csr_build_kernel<<<2048, 128, 0, stream>>>(inputs, inputsT, idxA, idxT, offA, offT);
    init_out_kernel<<<2048, 256, 0, stream>>>(first_a, first_t, out, srcAb, srcTb);

    for (int s = 0; s < 2; ++s) {
        // Phase A: a += bucket_t(update_t) x Awij2
        fused_phase_kernel<<<dim3(8, 64), 512, 0, stream>>>(idxA, offA, (const uint32_t*)srcTb, BtA, stateA);
        mirror_kernel<<<256, 256, 0, stream>>>(stateA, (uint32_t*)srcAb);
        // Phase T: t += bucket_j(new_a) x Awij
        fused_phase_kernel<<<dim3(8, 64), 512, 0, stream>>>(idxT, offT, (const uint32_t*)srcAb, BtT, stateT);
        if (s == 0)
            mirror_kernel<<<256, 256, 0, stream>>>(stateT, (uint32_t*)srcTb);
    }
}

// Round 6
// 298.328 us; speedup vs baseline: 1.1614x; 1.1614x over previous
//
#include <hip/hip_runtime.h>
#include <hip/hip_bf16.h>
#include <stdint.h>

// Problem constants: NA=NT=1024, A_DIM=E_DIM=128, L=128, K = L*128 = 16384

typedef short bf16x8 __attribute__((ext_vector_type(8)));
typedef float f32x4  __attribute__((ext_vector_type(4)));

#define GLD16(g, l) __builtin_amdgcn_global_load_lds( \
    (const __attribute__((address_space(1))) void*)(uintptr_t)(g), \
    (__attribute__((address_space(3))) void*)(uintptr_t)(l), 16, 0, 0)

#define BF_LO(v) __uint_as_float((v) << 16)
#define BF_HI(v) __uint_as_float((v) & 0xffff0000u)

// ---------------- prep: transpose inputs [1024][1024] -> inputsT ----------------
__global__ __launch_bounds__(256) void transpose_int_kernel(const int* __restrict__ in,
                                                            int* __restrict__ out) {
    __shared__ int tile[32][33];
    int b = blockIdx.x;              // 1024 tiles
    int tr = b >> 5, tc = b & 31;
    int r0 = tr * 32, c0 = tc * 32;
    int tx = threadIdx.x & 31, ty = threadIdx.x >> 5;
#pragma unroll
    for (int p = 0; p < 4; ++p)
        tile[ty + p * 8][tx] = in[(size_t)(r0 + ty + p * 8) * 1024 + c0 + tx];
    __syncthreads();
#pragma unroll
    for (int p = 0; p < 4; ++p) {
        int cc = ty + p * 8;
        out[(size_t)(c0 + cc) * 1024 + r0 + tx] = tile[tx][cc];
    }
}

// ------------- prep: transpose+cast weights f32 [16384][128] -> bf16 [128][16384] -------------
__global__ __launch_bounds__(256) void transpose_w_kernel(const float* __restrict__ W0,
                                                          const float* __restrict__ W1,
                                                          uint16_t* __restrict__ O0,
                                                          uint16_t* __restrict__ O1) {
    __shared__ float tile[32][33];
    int b = blockIdx.x;              // 4096 tiles (2048 per weight)
    const float* W = W0;
    uint16_t* O = O0;
    if (b >= 2048) { b -= 2048; W = W1; O = O1; }
    int tr = b >> 2, tc = b & 3;
    int r0 = tr * 32, c0 = tc * 32;
    int tx = threadIdx.x & 31, ty = threadIdx.x >> 5;
#pragma unroll
    for (int p = 0; p < 4; ++p)
        tile[ty + p * 8][tx] = W[(size_t)(r0 + ty + p * 8) * 128 + c0 + tx];
    __syncthreads();
#pragma unroll
    for (int p = 0; p < 4; ++p) {
        int cc = ty + p * 8;
        __hip_bfloat16 h = __float2bfloat16(tile[tx][cc]);
        O[(size_t)(c0 + cc) * 16384 + r0 + tx] = *(uint16_t*)&h;
    }
}

// ---------------- prep: CSR build — parallel deterministic counting sort ----------------
__global__ __launch_bounds__(128) void csr_build_kernel(const int* __restrict__ inA,
                                                        const int* __restrict__ inT,
                                                        uint16_t* __restrict__ idxA,
                                                        uint16_t* __restrict__ idxT,
                                                        int* __restrict__ offA,
                                                        int* __restrict__ offT) {
    __shared__ uint16_t chist[128][128];  // 32 KiB [chunk][label]
    __shared__ int lab[1024];
    __shared__ int tot[128];
    __shared__ int off[128];
    int b = blockIdx.x;
    const int* in = inA; uint16_t* idx = idxA; int* offo = offA; int row = b;
    if (b >= 1024) { in = inT; idx = idxT; offo = offT; row = b - 1024; }
    const int c = threadIdx.x;            // 0..127

    for (int i = c; i < 8192; i += 128) ((uint32_t*)chist)[i] = 0;
    for (int i = c; i < 1024; i += 128) lab[i] = in[(size_t)row * 1024 + i];
    __syncthreads();

    int mylab[8], rloc[8];
#pragma unroll
    for (int k = 0; k < 8; ++k) {
        int l = lab[c * 8 + k];
        mylab[k] = l;
        rloc[k] = chist[c][l];
        chist[c][l] = (uint16_t)(rloc[k] + 1);
    }
    __syncthreads();

    {   // column prefix over chunks: thread c owns label l=c
        int run = 0;
#pragma unroll 4
        for (int ch = 0; ch < 128; ++ch) {
            int v = chist[ch][c];
            chist[ch][c] = (uint16_t)run;
            run += v;
        }
        tot[c] = run;
    }
    __syncthreads();
    if (c == 0) {
        int s = 0;
#pragma unroll 4
        for (int l = 0; l < 128; ++l) { off[l] = s; s += tot[l]; }
    }
    __syncthreads();
    offo[(size_t)row * 128 + c] = off[c];
#pragma unroll
    for (int k = 0; k < 8; ++k) {
        int l = mylab[k];
        int pos = off[l] + (int)chist[c][l] + rloc[k];
        idx[(size_t)row * 1024 + pos] = (uint16_t)(c * 8 + k);
    }
}

// ---------------- prep: init output + bf16 mirrors (incl. zero row 1024) ----------------
__global__ __launch_bounds__(256) void init_out_kernel(const float* __restrict__ fa,
                                                       const float* __restrict__ ft,
                                                       float* __restrict__ out,
                                                       uint16_t* __restrict__ srcAb,
                                                       uint16_t* __restrict__ srcTb) {
    int i = blockIdx.x * 256 + threadIdx.x;   // grid 2048 -> 524288
    int r = i >> 8, c = i & 255;
    float v = 0.f;
    if (c < 128) {
        v = (r < 1024) ? fa[(size_t)r * 128 + c] : ft[(size_t)(r - 1024) * 128 + c];
        __hip_bfloat16 h = __float2bfloat16(v);
        if (r < 1024) srcAb[(size_t)r * 128 + c] = *(uint16_t*)&h;
        else          srcTb[(size_t)(r - 1024) * 128 + c] = *(uint16_t*)&h;
    }
    out[i] = v;
    if (i < 64) {   // dummy zero row (index 1024) used for segment padding
        ((uint32_t*)(srcAb + 1024 * 128))[i] = 0;
        ((uint32_t*)(srcTb + 1024 * 128))[i] = 0;
    }
}

// ---------------- mirror: state f32 (stride 256) -> bf16 (stride 128) ----------------
__global__ __launch_bounds__(256) void mirror_kernel(const float* __restrict__ state,
                                                     uint32_t* __restrict__ dst32) {
    int i = blockIdx.x * 256 + threadIdx.x;   // grid 256 -> 65536 threads, 2 floats each
    int idx2 = i * 2;
    int r = idx2 >> 7, c = idx2 & 127;
    float2 v = *(const float2*)(state + (size_t)r * 256 + c);
    __hip_bfloat16 h0 = __float2bfloat16(v.x), h1 = __float2bfloat16(v.y);
    dst32[i] = ((uint32_t)(*(uint16_t*)&h1) << 16) | (uint32_t)(*(uint16_t*)&h0);
}

// ---------------- fused bucket+GEMM phase (v2: LDS-staged indices, dual-row ILP) ----------------
// Block (mt, lc): rows [mt*128, +128), labels {2lc, 2lc+1}. 8 waves, 2 blocks/CU.
__global__ __launch_bounds__(512, 4) void fused_phase_kernel(
    const uint16_t* __restrict__ idx,   // [1024][1024] CSR indices (sorted by label)
    const int* __restrict__ off,        // [1024][128] label offsets
    const uint32_t* __restrict__ srcb,  // [1025][64] packed bf16x2 source (row 1024 = zeros)
    const uint16_t* __restrict__ Bt,    // [128][16384] bf16 weights (n-major)
    float* __restrict__ state)          // [1024][256] f32 accumulator (d_out)
{
    __shared__ uint16_t Atile[128 * 128];        // 32 KiB, 16B-slot XOR-swizzled by row&15
    __shared__ uint16_t Btile[128 * 128];        // 32 KiB, same swizzle
    __shared__ uint16_t sidx[128][48];           // 12 KiB, padded label-pair segments
    __shared__ int rA[128], rB[128], rS0[128], rS1[128], rF[128];   // 2.5 KiB

    const int tid = threadIdx.x;
    const int lane = tid & 63, wv = tid >> 6;
    const int mt = blockIdx.x;          // 0..7
    const int lc = blockIdx.y;          // 0..63
    const int l0 = lc * 2;
    const int wr = wv >> 2, wc = wv & 3;

    // ---- stage per-row segment info (128 threads, 3 loads each) ----
    if (tid < 128) {
        const int* ro = off + (size_t)(mt * 128 + tid) * 128;
        int s0 = ro[l0];
        int s1 = ro[l0 + 1];
        int s2 = (l0 + 2 < 128) ? ro[l0 + 2] : 1024;
        int len0 = s1 - s0, len1 = s2 - s1;
        int n0 = (len0 + 3) & ~3, n1 = (len1 + 3) & ~3;
        rA[tid] = len0; rB[tid] = len1; rS0[tid] = s0; rS1[tid] = s1;
        rF[tid] = (n0 + n1 > 48);
    }
    __syncthreads();
    // ---- stage indices into LDS, padded to x4 with 1024 (zero row) ----
    {
        int r = tid >> 2, q = tid & 3;
        if (!rF[r]) {
            int len0 = rA[r], len1 = rB[r];
            int n0 = (len0 + 3) & ~3, n1 = (len1 + 3) & ~3;
            const uint16_t* g0 = idx + (size_t)(mt * 128 + r) * 1024 + rS0[r];
            for (int p = q; p < n0; p += 4) sidx[r][p] = (p < len0) ? g0[p] : (uint16_t)1024;
            const uint16_t* g1 = idx + (size_t)(mt * 128 + r) * 1024 + rS1[r];
            for (int p = q; p < n1; p += 4) sidx[r][n0 + p] = (p < len1) ? g1[p] : (uint16_t)1024;
        }
    }
    __syncthreads();

    f32x4 acc[4][2] = {};
    const int brr = lane >> 4;          // 0..3
    const int bx  = lane & 15;          // 16B slot

    for (int ls = 0; ls < 2; ++ls) {
        const int l = l0 + ls;

        // ---- B stage: async global_load_lds, inverse-swizzled source ----
#pragma unroll
        for (int g = 0; g < 4; ++g) {
            int row = wv * 16 + g * 4 + brr;
            int sx = bx ^ (row & 15);
            const char* gB = (const char*)Bt + ((size_t)row * 16384 + l * 128 + sx * 8) * 2;
            char* lB = (char*)Btile + (wv * 16 + g * 4) * 256;   // +lane*16 by hardware
            GLD16(gB, lB);
        }

        // ---- A store helper ----
        auto store_a = [&](int jl, float v0, float v1) {
            __hip_bfloat16 h0 = __float2bfloat16(v0), h1 = __float2bfloat16(v1);
            uint32_t pk = ((uint32_t)(*(uint16_t*)&h1) << 16) | (uint32_t)(*(uint16_t*)&h0);
            int phys = (lane >> 2) ^ (jl & 15);
            *(uint32_t*)((char*)Atile + jl * 256 + phys * 16 + (lane & 3) * 4) = pk;
        };
        // ---- slow path (rare): direct-global indices, bounds-checked ----
        auto slow_row = [&](int r) {
            int start = ls ? rS1[r] : rS0[r];
            int len   = ls ? rB[r]  : rA[r];
            const uint16_t* ig = idx + (size_t)(mt * 128 + r) * 1024 + start;
            float c0 = 0.f, c1 = 0.f, d0 = 0.f, d1 = 0.f;
            int p = 0;
            for (; p + 3 < len; p += 4) {
                uint32_t v0 = srcb[(size_t)ig[p]     * 64 + lane];
                uint32_t v1 = srcb[(size_t)ig[p + 1] * 64 + lane];
                uint32_t v2 = srcb[(size_t)ig[p + 2] * 64 + lane];
                uint32_t v3 = srcb[(size_t)ig[p + 3] * 64 + lane];
                c0 += BF_LO(v0) + BF_LO(v1); c1 += BF_HI(v0) + BF_HI(v1);
                d0 += BF_LO(v2) + BF_LO(v3); d1 += BF_HI(v2) + BF_HI(v3);
            }
            for (; p < len; ++p) {
                uint32_t v0 = srcb[(size_t)ig[p] * 64 + lane];
                c0 += BF_LO(v0); c1 += BF_HI(v0);
            }
            store_a(r, c0 + d0, c1 + d1);
        };

        // ---- gather: each wave owns 16 rows, processed in interleaved pairs ----
#pragma unroll 1
        for (int jj = 0; jj < 16; jj += 2) {
            int ra = wv * 16 + jj, rb = ra + 1;
            if (!rF[ra] && !rF[rb]) {
                int nA = ((ls ? rB[ra] : rA[ra]) + 3) & ~3;
                int baseA = ls ? ((rA[ra] + 3) & ~3) : 0;
                int nB = ((ls ? rB[rb] : rA[rb]) + 3) & ~3;
                int baseB = ls ? ((rA[rb] + 3) & ~3) : 0;
                const uint16_t* iA = &sidx[ra][baseA];
                const uint16_t* iB = &sidx[rb][baseB];
                float xa0 = 0.f, xa1 = 0.f, ya0 = 0.f, ya1 = 0.f;
                float xb0 = 0.f, xb1 = 0.f, yb0 = 0.f, yb1 = 0.f;
                int nmax = nA > nB ? nA : nB;
#pragma unroll 1
                for (int p = 0; p < nmax; p += 4) {
                    if (p < nA) {
                        ushort4 t = *(const ushort4*)(iA + p);   // one ds_read_b64
                        uint32_t v0 = srcb[(size_t)t.x * 64 + lane];
                        uint32_t v1 = srcb[(size_t)t.y * 64 + lane];
                        uint32_t v2 = srcb[(size_t)t.z * 64 + lane];
                        uint32_t v3 = srcb[(size_t)t.w * 64 + lane];
                        xa0 += BF_LO(v0) + BF_LO(v1); xa1 += BF_HI(v0) + BF_HI(v1);
                        ya0 += BF_LO(v2) + BF_LO(v3); ya1 += BF_HI(v2) + BF_HI(v3);
                    }
                    if (p < nB) {
                        ushort4 t = *(const ushort4*)(iB + p);
                        uint32_t v0 = srcb[(size_t)t.x * 64 + lane];
                        uint32_t v1 = srcb[(size_t)t.y * 64 + lane];
                        uint32_t v2 = srcb[(size_t)t.z * 64 + lane];
                        uint32_t v3 = srcb[(size_t)t.w * 64 + lane];
                        xb0 += BF_LO(v0) + BF_LO(v1); xb1 += BF_HI(v0) + BF_HI(v1);
                        yb0 += BF_LO(v2) + BF_LO(v3); yb1 += BF_HI(v2) + BF_HI(v3);
                    }
                }
                store_a(ra, xa0 + ya0, xa1 + ya1);
                store_a(rb, xb0 + yb0, xb1 + yb1);
            } else {
                slow_row(ra);
                slow_row(rb);
            }
        }
        __syncthreads();   // drains GLD16 vmcnt + orders LDS writes

        // ---- MFMA: wave tile 64x32, K=128 ----
        {
            const int q = lane >> 4, rl = lane & 15;
#pragma unroll
            for (int kk = 0; kk < 4; ++kk) {
                bf16x8 af[4], bfr[2];
#pragma unroll
                for (int m = 0; m < 4; ++m) {
                    int row = wr * 64 + m * 16 + rl;
                    int sw = (kk * 4 + q) ^ (row & 15);
                    af[m] = *(const bf16x8*)((const char*)Atile + row * 256 + sw * 16);
                }
#pragma unroll
                for (int n = 0; n < 2; ++n) {
                    int row = wc * 32 + n * 16 + rl;
                    int sw = (kk * 4 + q) ^ (row & 15);
                    bfr[n] = *(const bf16x8*)((const char*)Btile + row * 256 + sw * 16);
                }
#pragma unroll
                for (int m = 0; m < 4; ++m)
#pragma unroll
                    for (int n = 0; n < 2; ++n)
                        acc[m][n] = __builtin_amdgcn_mfma_f32_16x16x32_bf16(af[m], bfr[n], acc[m][n], 0, 0, 0);
            }
        }
        __syncthreads();   // before next label overwrites A/B tiles
    }

    // ---- epilogue: C/D layout col=lane&15, row=(lane>>4)*4+reg ----
    const int rq = lane >> 4, cn = lane & 15;
#pragma unroll
    for (int m = 0; m < 4; ++m)
#pragma unroll
        for (int n = 0; n < 2; ++n)
#pragma unroll
            for (int r = 0; r < 4; ++r) {
                int row = mt * 128 + wr * 64 + m * 16 + rq * 4 + r;
                int col = wc * 32 + n * 16 + cn;
                unsafeAtomicAdd(&state[(size_t)row * 256 + col], acc[m][n][r]);
            }
}

extern "C" void kernel_launch(void* const* d_in, const int* in_sizes, int n_in,
                              void* d_out, int out_size, void* d_ws, size_t ws_size,
                              hipStream_t stream) {
    const int*   inputs  = (const int*)d_in[0];
    const float* first_a = (const float*)d_in[1];
    const float* first_t = (const float*)d_in[2];
    const float* Awij    = (const float*)d_in[3];
    const float* Awij2   = (const float*)d_in[4];
    float* out = (float*)d_out;

    // workspace layout (18 MiB total)
    char* w = (char*)d_ws;
    int*      inputsT = (int*)(w);                      // 4 MiB (prep-only)
    uint16_t* BtA     = (uint16_t*)(w + (4u << 20));    // 4 MiB  [a][l*128+e] = Awij2[l][e][a]
    uint16_t* BtT     = (uint16_t*)(w + (8u << 20));    // 4 MiB  [e][l*128+a] = Awij[l][a][e]
    uint16_t* idxA    = (uint16_t*)(w + (12u << 20));   // 2 MiB
    uint16_t* idxT    = (uint16_t*)(w + (14u << 20));   // 2 MiB
    int*      offA    = (int*)(w + (16u << 20));        // 512 KiB
    int*      offT    = (int*)(w + (16u << 20) + (1u << 19)); // 512 KiB
    uint16_t* srcAb   = (uint16_t*)(w + (17u << 20));   // 256.25 KiB: [1025][128] bf16
    uint16_t* srcTb   = (uint16_t*)(w + (17u << 20) + (384u << 10)); // [1025][128] bf16
    if (ws_size < (18u << 20)) return;

    float* stateA = out;                 // [1024][256], cols 0..127 live
    float* stateT = out + 1024 * 256;    // [1024][256], cols 0..127 live

    transpose_int_kernel<<<1024, 256, 0, stream>>>(inputs, inputsT);
    transpose_w_kernel<<<4096, 256, 0, stream>>>(Awij2, Awij, BtA, BtT);
    csr_build_kernel<<<2048, 128, 0, stream>>>(inputs, inputsT, idxA, idxT, offA, offT);
    init_out_kernel<<<2048, 256, 0, stream>>>(first_a, first_t, out, srcAb, srcTb);

    for (int s = 0; s < 2; ++s) {
        // Phase A: a += bucket_t(update_t) x Awij2
        fused_phase_kernel<<<dim3(8, 64), 512, 0, stream>>>(idxA, offA, (const uint32_t*)srcTb, BtA, stateA);
        mirror_kernel<<<256, 256, 0, stream>>>(stateA, (uint32_t*)srcAb);
        // Phase T: t += bucket_j(new_a) x Awij
        fused_phase_kernel<<<dim3(8, 64), 512, 0, stream>>>(idxT, offT, (const uint32_t*)srcAb, BtT, stateT);
        if (s == 0)
            mirror_kernel<<<256, 256, 0, stream>>>(stateT, (uint32_t*)srcTb);
    }
}

// Round 7
// 235.239 us; speedup vs baseline: 1.4729x; 1.2682x over previous
//
#include <hip/hip_runtime.h>
#include <hip/hip_bf16.h>
#include <stdint.h>

// Problem constants: NA=NT=1024, A_DIM=E_DIM=128, L=128, K = L*128 = 16384

typedef short bf16x8 __attribute__((ext_vector_type(8)));
typedef float f32x4  __attribute__((ext_vector_type(4)));

#define GLD16(g, l) __builtin_amdgcn_global_load_lds( \
    (const __attribute__((address_space(1))) void*)(uintptr_t)(g), \
    (__attribute__((address_space(3))) void*)(uintptr_t)(l), 16, 0, 0)

#define BF_LO(v) __uint_as_float((v) << 16)
#define BF_HI(v) __uint_as_float((v) & 0xffff0000u)

// ---------------- prep: transpose inputs [1024][1024] -> inputsT ----------------
__global__ __launch_bounds__(256) void transpose_int_kernel(const int* __restrict__ in,
                                                            int* __restrict__ out) {
    __shared__ int tile[32][33];
    int b = blockIdx.x;              // 1024 tiles
    int tr = b >> 5, tc = b & 31;
    int r0 = tr * 32, c0 = tc * 32;
    int tx = threadIdx.x & 31, ty = threadIdx.x >> 5;
#pragma unroll
    for (int p = 0; p < 4; ++p)
        tile[ty + p * 8][tx] = in[(size_t)(r0 + ty + p * 8) * 1024 + c0 + tx];
    __syncthreads();
#pragma unroll
    for (int p = 0; p < 4; ++p) {
        int cc = ty + p * 8;
        out[(size_t)(c0 + cc) * 1024 + r0 + tx] = tile[tx][cc];
    }
}

// ------------- prep: transpose+cast weights f32 [16384][128] -> bf16 [128][16384] -------------
__global__ __launch_bounds__(256) void transpose_w_kernel(const float* __restrict__ W0,
                                                          const float* __restrict__ W1,
                                                          uint16_t* __restrict__ O0,
                                                          uint16_t* __restrict__ O1) {
    __shared__ float tile[32][33];
    int b = blockIdx.x;              // 4096 tiles (2048 per weight)
    const float* W = W0;
    uint16_t* O = O0;
    if (b >= 2048) { b -= 2048; W = W1; O = O1; }
    int tr = b >> 2, tc = b & 3;
    int r0 = tr * 32, c0 = tc * 32;
    int tx = threadIdx.x & 31, ty = threadIdx.x >> 5;
#pragma unroll
    for (int p = 0; p < 4; ++p)
        tile[ty + p * 8][tx] = W[(size_t)(r0 + ty + p * 8) * 128 + c0 + tx];
    __syncthreads();
#pragma unroll
    for (int p = 0; p < 4; ++p) {
        int cc = ty + p * 8;
        __hip_bfloat16 h = __float2bfloat16(tile[tx][cc]);
        O[(size_t)(c0 + cc) * 16384 + r0 + tx] = *(uint16_t*)&h;
    }
}

// ---------------- prep: CSR build — parallel deterministic counting sort ----------------
__global__ __launch_bounds__(128) void csr_build_kernel(const int* __restrict__ inA,
                                                        const int* __restrict__ inT,
                                                        uint16_t* __restrict__ idxA,
                                                        uint16_t* __restrict__ idxT,
                                                        int* __restrict__ offA,
                                                        int* __restrict__ offT) {
    __shared__ uint16_t chist[128][128];  // 32 KiB [chunk][label]
    __shared__ int lab[1024];
    __shared__ int tot[128];
    __shared__ int off[128];
    int b = blockIdx.x;
    const int* in = inA; uint16_t* idx = idxA; int* offo = offA; int row = b;
    if (b >= 1024) { in = inT; idx = idxT; offo = offT; row = b - 1024; }
    const int c = threadIdx.x;            // 0..127

    for (int i = c; i < 8192; i += 128) ((uint32_t*)chist)[i] = 0;
    for (int i = c; i < 1024; i += 128) lab[i] = in[(size_t)row * 1024 + i];
    __syncthreads();

    int mylab[8], rloc[8];
#pragma unroll
    for (int k = 0; k < 8; ++k) {
        int l = lab[c * 8 + k];
        mylab[k] = l;
        rloc[k] = chist[c][l];
        chist[c][l] = (uint16_t)(rloc[k] + 1);
    }
    __syncthreads();

    {   // column prefix over chunks: thread c owns label l=c
        int run = 0;
#pragma unroll 4
        for (int ch = 0; ch < 128; ++ch) {
            int v = chist[ch][c];
            chist[ch][c] = (uint16_t)run;
            run += v;
        }
        tot[c] = run;
    }
    __syncthreads();
    if (c == 0) {
        int s = 0;
#pragma unroll 4
        for (int l = 0; l < 128; ++l) { off[l] = s; s += tot[l]; }
    }
    __syncthreads();
    offo[(size_t)row * 128 + c] = off[c];
#pragma unroll
    for (int k = 0; k < 8; ++k) {
        int l = mylab[k];
        int pos = off[l] + (int)chist[c][l] + rloc[k];
        idx[(size_t)row * 1024 + pos] = (uint16_t)(c * 8 + k);
    }
}

// ---------------- prep: init output + bf16 mirrors (incl. zero row 1024) ----------------
__global__ __launch_bounds__(256) void init_out_kernel(const float* __restrict__ fa,
                                                       const float* __restrict__ ft,
                                                       float* __restrict__ out,
                                                       uint16_t* __restrict__ srcAb,
                                                       uint16_t* __restrict__ srcTb) {
    int i = blockIdx.x * 256 + threadIdx.x;   // grid 2048 -> 524288
    int r = i >> 8, c = i & 255;
    float v = 0.f;
    if (c < 128) {
        v = (r < 1024) ? fa[(size_t)r * 128 + c] : ft[(size_t)(r - 1024) * 128 + c];
        __hip_bfloat16 h = __float2bfloat16(v);
        if (r < 1024) srcAb[(size_t)r * 128 + c] = *(uint16_t*)&h;
        else          srcTb[(size_t)(r - 1024) * 128 + c] = *(uint16_t*)&h;
    }
    out[i] = v;
    if (i < 64) {   // dummy zero row (index 1024) used for segment padding
        ((uint32_t*)(srcAb + 1024 * 128))[i] = 0;
        ((uint32_t*)(srcTb + 1024 * 128))[i] = 0;
    }
}

// ---------------- reduce partials + update state + emit bf16 mirror ----------------
// partial[1024][64][128]: per-row, 64 lc-partials. Sum in fixed order (deterministic),
// add into state (stride 256), write bf16 mirror (stride 128).
__global__ __launch_bounds__(256) void reduce_mirror_kernel(const float* __restrict__ partial,
                                                            float* __restrict__ state,
                                                            uint16_t* __restrict__ mirror) {
    const int r = blockIdx.x * 8 + (threadIdx.x >> 5);   // grid 128 -> rows 0..1023
    const int c4 = (threadIdx.x & 31) * 4;               // col group of 4
    const f32x4* p = (const f32x4*)(partial + ((size_t)r * 64) * 128 + c4);
    f32x4 s = {};
#pragma unroll 16
    for (int lc = 0; lc < 64; ++lc) s += p[lc * 32];     // stride 128 floats
    f32x4 v = *(f32x4*)(state + (size_t)r * 256 + c4);
    v += s;
    *(f32x4*)(state + (size_t)r * 256 + c4) = v;
    __hip_bfloat16 h0 = __float2bfloat16(v[0]), h1 = __float2bfloat16(v[1]);
    __hip_bfloat16 h2 = __float2bfloat16(v[2]), h3 = __float2bfloat16(v[3]);
    uint2 pk;
    pk.x = ((uint32_t)(*(uint16_t*)&h1) << 16) | (uint32_t)(*(uint16_t*)&h0);
    pk.y = ((uint32_t)(*(uint16_t*)&h3) << 16) | (uint32_t)(*(uint16_t*)&h2);
    *(uint2*)(mirror + (size_t)r * 128 + c4) = pk;
}

// ---------------- fused bucket+GEMM phase (v3: partial stores, no atomics) ----------------
// Block (mt, lc): rows [mt*128, +128), labels {2lc, 2lc+1}. 8 waves, 2 blocks/CU.
__global__ __launch_bounds__(512, 4) void fused_phase_kernel(
    const uint16_t* __restrict__ idx,   // [1024][1024] CSR indices (sorted by label)
    const int* __restrict__ off,        // [1024][128] label offsets
    const uint32_t* __restrict__ srcb,  // [1025][64] packed bf16x2 source (row 1024 = zeros)
    const uint16_t* __restrict__ Bt,    // [128][16384] bf16 weights (n-major)
    float* __restrict__ partial)        // [1024][64][128] per-(row,lc) partials
{
    __shared__ uint16_t Atile[128 * 128];        // 32 KiB, 16B-slot XOR-swizzled by row&15
    __shared__ uint16_t Btile[128 * 128];        // 32 KiB, same swizzle
    __shared__ uint16_t sidx[128][48];           // 12 KiB, padded label-pair segments
    __shared__ int rA[128], rB[128], rS0[128], rS1[128], rF[128];   // 2.5 KiB

    const int tid = threadIdx.x;
    const int lane = tid & 63, wv = tid >> 6;
    const int mt = blockIdx.x;          // 0..7
    const int lc = blockIdx.y;          // 0..63
    const int l0 = lc * 2;
    const int wr = wv >> 2, wc = wv & 3;

    // ---- stage per-row segment info (128 threads, 3 loads each) ----
    if (tid < 128) {
        const int* ro = off + (size_t)(mt * 128 + tid) * 128;
        int s0 = ro[l0];
        int s1 = ro[l0 + 1];
        int s2 = (l0 + 2 < 128) ? ro[l0 + 2] : 1024;
        int len0 = s1 - s0, len1 = s2 - s1;
        int n0 = (len0 + 3) & ~3, n1 = (len1 + 3) & ~3;
        rA[tid] = len0; rB[tid] = len1; rS0[tid] = s0; rS1[tid] = s1;
        rF[tid] = (n0 + n1 > 48);
    }
    __syncthreads();
    // ---- stage indices into LDS, padded to x4 with 1024 (zero row) ----
    {
        int r = tid >> 2, q = tid & 3;
        if (!rF[r]) {
            int len0 = rA[r], len1 = rB[r];
            int n0 = (len0 + 3) & ~3, n1 = (len1 + 3) & ~3;
            const uint16_t* g0 = idx + (size_t)(mt * 128 + r) * 1024 + rS0[r];
            for (int p = q; p < n0; p += 4) sidx[r][p] = (p < len0) ? g0[p] : (uint16_t)1024;
            const uint16_t* g1 = idx + (size_t)(mt * 128 + r) * 1024 + rS1[r];
            for (int p = q; p < n1; p += 4) sidx[r][n0 + p] = (p < len1) ? g1[p] : (uint16_t)1024;
        }
    }
    __syncthreads();

    f32x4 acc[4][2] = {};
    const int brr = lane >> 4;          // 0..3
    const int bx  = lane & 15;          // 16B slot

    for (int ls = 0; ls < 2; ++ls) {
        const int l = l0 + ls;

        // ---- B stage: async global_load_lds, inverse-swizzled source ----
#pragma unroll
        for (int g = 0; g < 4; ++g) {
            int row = wv * 16 + g * 4 + brr;
            int sx = bx ^ (row & 15);
            const char* gB = (const char*)Bt + ((size_t)row * 16384 + l * 128 + sx * 8) * 2;
            char* lB = (char*)Btile + (wv * 16 + g * 4) * 256;   // +lane*16 by hardware
            GLD16(gB, lB);
        }

        // ---- A store helper ----
        auto store_a = [&](int jl, float v0, float v1) {
            __hip_bfloat16 h0 = __float2bfloat16(v0), h1 = __float2bfloat16(v1);
            uint32_t pk = ((uint32_t)(*(uint16_t*)&h1) << 16) | (uint32_t)(*(uint16_t*)&h0);
            int phys = (lane >> 2) ^ (jl & 15);
            *(uint32_t*)((char*)Atile + jl * 256 + phys * 16 + (lane & 3) * 4) = pk;
        };
        // ---- slow path (rare): direct-global indices, bounds-checked ----
        auto slow_row = [&](int r) {
            int start = ls ? rS1[r] : rS0[r];
            int len   = ls ? rB[r]  : rA[r];
            const uint16_t* ig = idx + (size_t)(mt * 128 + r) * 1024 + start;
            float c0 = 0.f, c1 = 0.f, d0 = 0.f, d1 = 0.f;
            int p = 0;
            for (; p + 3 < len; p += 4) {
                uint32_t v0 = srcb[(size_t)ig[p]     * 64 + lane];
                uint32_t v1 = srcb[(size_t)ig[p + 1] * 64 + lane];
                uint32_t v2 = srcb[(size_t)ig[p + 2] * 64 + lane];
                uint32_t v3 = srcb[(size_t)ig[p + 3] * 64 + lane];
                c0 += BF_LO(v0) + BF_LO(v1); c1 += BF_HI(v0) + BF_HI(v1);
                d0 += BF_LO(v2) + BF_LO(v3); d1 += BF_HI(v2) + BF_HI(v3);
            }
            for (; p < len; ++p) {
                uint32_t v0 = srcb[(size_t)ig[p] * 64 + lane];
                c0 += BF_LO(v0); c1 += BF_HI(v0);
            }
            store_a(r, c0 + d0, c1 + d1);
        };

        // ---- gather: each wave owns 16 rows, processed in interleaved pairs ----
#pragma unroll 1
        for (int jj = 0; jj < 16; jj += 2) {
            int ra = wv * 16 + jj, rb = ra + 1;
            if (!rF[ra] && !rF[rb]) {
                int nA = ((ls ? rB[ra] : rA[ra]) + 3) & ~3;
                int baseA = ls ? ((rA[ra] + 3) & ~3) : 0;
                int nB = ((ls ? rB[rb] : rA[rb]) + 3) & ~3;
                int baseB = ls ? ((rA[rb] + 3) & ~3) : 0;
                const uint16_t* iA = &sidx[ra][baseA];
                const uint16_t* iB = &sidx[rb][baseB];
                float xa0 = 0.f, xa1 = 0.f, ya0 = 0.f, ya1 = 0.f;
                float xb0 = 0.f, xb1 = 0.f, yb0 = 0.f, yb1 = 0.f;
                int nmax = nA > nB ? nA : nB;
#pragma unroll 1
                for (int p = 0; p < nmax; p += 4) {
                    if (p < nA) {
                        ushort4 t = *(const ushort4*)(iA + p);   // one ds_read_b64
                        uint32_t v0 = srcb[(size_t)t.x * 64 + lane];
                        uint32_t v1 = srcb[(size_t)t.y * 64 + lane];
                        uint32_t v2 = srcb[(size_t)t.z * 64 + lane];
                        uint32_t v3 = srcb[(size_t)t.w * 64 + lane];
                        xa0 += BF_LO(v0) + BF_LO(v1); xa1 += BF_HI(v0) + BF_HI(v1);
                        ya0 += BF_LO(v2) + BF_LO(v3); ya1 += BF_HI(v2) + BF_HI(v3);
                    }
                    if (p < nB) {
                        ushort4 t = *(const ushort4*)(iB + p);
                        uint32_t v0 = srcb[(size_t)t.x * 64 + lane];
                        uint32_t v1 = srcb[(size_t)t.y * 64 + lane];
                        uint32_t v2 = srcb[(size_t)t.z * 64 + lane];
                        uint32_t v3 = srcb[(size_t)t.w * 64 + lane];
                        xb0 += BF_LO(v0) + BF_LO(v1); xb1 += BF_HI(v0) + BF_HI(v1);
                        yb0 += BF_LO(v2) + BF_LO(v3); yb1 += BF_HI(v2) + BF_HI(v3);
                    }
                }
                store_a(ra, xa0 + ya0, xa1 + ya1);
                store_a(rb, xb0 + yb0, xb1 + yb1);
            } else {
                slow_row(ra);
                slow_row(rb);
            }
        }
        __syncthreads();   // drains GLD16 vmcnt + orders LDS writes

        // ---- MFMA: wave tile 64x32, K=128 ----
        {
            const int q = lane >> 4, rl = lane & 15;
#pragma unroll
            for (int kk = 0; kk < 4; ++kk) {
                bf16x8 af[4], bfr[2];
#pragma unroll
                for (int m = 0; m < 4; ++m) {
                    int row = wr * 64 + m * 16 + rl;
                    int sw = (kk * 4 + q) ^ (row & 15);
                    af[m] = *(const bf16x8*)((const char*)Atile + row * 256 + sw * 16);
                }
#pragma unroll
                for (int n = 0; n < 2; ++n) {
                    int row = wc * 32 + n * 16 + rl;
                    int sw = (kk * 4 + q) ^ (row & 15);
                    bfr[n] = *(const bf16x8*)((const char*)Btile + row * 256 + sw * 16);
                }
#pragma unroll
                for (int m = 0; m < 4; ++m)
#pragma unroll
                    for (int n = 0; n < 2; ++n)
                        acc[m][n] = __builtin_amdgcn_mfma_f32_16x16x32_bf16(af[m], bfr[n], acc[m][n], 0, 0, 0);
            }
        }
        __syncthreads();   // before next label overwrites A/B tiles
    }

    // ---- epilogue: plain stores to private partial slice (no atomics) ----
    // C/D layout: col=lane&15, row=(lane>>4)*4+reg
    const int rq = lane >> 4, cn = lane & 15;
#pragma unroll
    for (int m = 0; m < 4; ++m)
#pragma unroll
        for (int n = 0; n < 2; ++n)
#pragma unroll
            for (int r = 0; r < 4; ++r) {
                int row = mt * 128 + wr * 64 + m * 16 + rq * 4 + r;
                int col = wc * 32 + n * 16 + cn;
                partial[((size_t)row * 64 + lc) * 128 + col] = acc[m][n][r];
            }
}

extern "C" void kernel_launch(void* const* d_in, const int* in_sizes, int n_in,
                              void* d_out, int out_size, void* d_ws, size_t ws_size,
                              hipStream_t stream) {
    const int*   inputs  = (const int*)d_in[0];
    const float* first_a = (const float*)d_in[1];
    const float* first_t = (const float*)d_in[2];
    const float* Awij    = (const float*)d_in[3];
    const float* Awij2   = (const float*)d_in[4];
    float* out = (float*)d_out;

    // workspace layout (50 MiB total; d_ws is 256 MiB per harness fill counters)
    char* w = (char*)d_ws;
    int*      inputsT = (int*)(w);                      // 4 MiB (prep-only)
    uint16_t* BtA     = (uint16_t*)(w + (4u << 20));    // 4 MiB  [a][l*128+e] = Awij2[l][e][a]
    uint16_t* BtT     = (uint16_t*)(w + (8u << 20));    // 4 MiB  [e][l*128+a] = Awij[l][a][e]
    uint16_t* idxA    = (uint16_t*)(w + (12u << 20));   // 2 MiB
    uint16_t* idxT    = (uint16_t*)(w + (14u << 20));   // 2 MiB
    int*      offA    = (int*)(w + (16u << 20));        // 512 KiB
    int*      offT    = (int*)(w + (16u << 20) + (1u << 19)); // 512 KiB
    uint16_t* srcAb   = (uint16_t*)(w + (17u << 20));   // [1025][128] bf16
    uint16_t* srcTb   = (uint16_t*)(w + (17u << 20) + (384u << 10)); // [1025][128] bf16
    float*    partial = (float*)(w + (18u << 20));      // 32 MiB  [1024][64][128] f32
    if (ws_size < (50u << 20)) return;

    float* stateA = out;                 // [1024][256], cols 0..127 live
    float* stateT = out + 1024 * 256;    // [1024][256], cols 0..127 live

    transpose_int_kernel<<<1024, 256, 0, stream>>>(inputs, inputsT);
    transpose_w_kernel<<<4096, 256, 0, stream>>>(Awij2, Awij, BtA, BtT);
    csr_build_kernel<<<2048, 128, 0, stream>>>(inputs, inputsT, idxA, idxT, offA, offT);
    init_out_kernel<<<2048, 256, 0, stream>>>(first_a, first_t, out, srcAb, srcTb);

    for (int s = 0; s < 2; ++s) {
        // Phase A: a += bucket_t(update_t) x Awij2
        fused_phase_kernel<<<dim3(8, 64), 512, 0, stream>>>(idxA, offA, (const uint32_t*)srcTb, BtA, partial);
        reduce_mirror_kernel<<<128, 256, 0, stream>>>(partial, stateA, srcAb);
        // Phase T: t += bucket_j(new_a) x Awij
        fused_phase_kernel<<<dim3(8, 64), 512, 0, stream>>>(idxT, offT, (const uint32_t*)srcAb, BtT, partial);
        reduce_mirror_kernel<<<128, 256, 0, stream>>>(partial, stateT, srcTb);
    }
}